// Round 1
// baseline (1142.422 us; speedup 1.0000x reference)
//
#include <hip/hip_runtime.h>
#include <math.h>

#define B_    2
#define C_    1536
#define S_    16384
#define H_    768
#define T_    367
#define P_    128
#define HALF_ 384
#define TT_   734                 // 2*T
#define PRED_ELEMS 24051712      // B*P*P*2T

// ws layout (float offsets)
#define XC_OFF 0                 // [B][4][P][C]   1,572,864 floats
#define XH_OFF 1572864           // [B][4][P][H]     786,432 floats
#define CS_OFF 2359296           // [B][4][P][HALF] float2  786,432 floats
// total ws use: 12.6 MB

// ---------------- A0: gather embedding columns ----------------
__global__ void gather_cols(const float* __restrict__ emb,
                            const int* __restrict__ sp,
                            float* __restrict__ xc) {
    int blk = blockIdx.x;           // B*4*P = 1024
    int p = blk & 127;
    int g = (blk >> 7) & 3;
    int b = blk >> 9;
    int s = sp[(b * 4 + g) * P_ + p];
    const float* src = emb + (size_t)b * C_ * S_ + s;
    float* dst = xc + ((size_t)(b * 4 + g) * P_ + p) * C_;
    for (int c = threadIdx.x; c < C_; c += blockDim.x)
        dst[c] = src[(size_t)c * S_];
}

// ---------------- A1: gathered-logits GEMM + bias ----------------
// rows r in [0,1024): r = (b*4+g)*128+p ; xh[r][h] = sum_c xc[r][c]*w[o][h][c] + bias[o][h]
__global__ __launch_bounds__(256) void small_gemm(const float* __restrict__ xc,
                                                  const float* __restrict__ w,
                                                  const float* __restrict__ bias,
                                                  const int* __restrict__ org,
                                                  float* __restrict__ xh) {
    __shared__ float Xs[64][33];
    __shared__ float Ws[64][33];
    int b = blockIdx.x, rt = blockIdx.y, ht = blockIdx.z;
    int o = org[b];
    int row0 = b * 512 + rt * 64;
    int h0 = ht * 64;
    int tid = threadIdx.x;
    int tx = tid & 15, ty = tid >> 4;
    float acc[4][4] = {};
    for (int k0 = 0; k0 < C_; k0 += 32) {
        for (int e = tid; e < 64 * 32; e += 256) {
            int i = e >> 5, k = e & 31;
            Xs[i][k] = xc[(size_t)(row0 + i) * C_ + k0 + k];
            Ws[i][k] = w[((size_t)o * H_ + h0 + i) * C_ + k0 + k];
        }
        __syncthreads();
        for (int k = 0; k < 32; ++k) {
            float a_[4], b_[4];
            #pragma unroll
            for (int u = 0; u < 4; ++u) a_[u] = Xs[ty * 4 + u][k];
            #pragma unroll
            for (int v = 0; v < 4; ++v) b_[v] = Ws[tx * 4 + v][k];
            #pragma unroll
            for (int u = 0; u < 4; ++u)
                #pragma unroll
                for (int v = 0; v < 4; ++v) acc[u][v] += a_[u] * b_[v];
        }
        __syncthreads();
    }
    for (int u = 0; u < 4; ++u)
        for (int v = 0; v < 4; ++v) {
            int r = row0 + ty * 4 + u, h = h0 + tx * 4 + v;
            xh[(size_t)r * H_ + h] = acc[u][v] + bias[o * H_ + h];
        }
}

// ---------------- A2: RoPE cos/sin table (fp64 trig for accuracy) ----------------
__global__ void rope_table(const int* __restrict__ sp, float2* __restrict__ cs) {
    int e = blockIdx.x * blockDim.x + threadIdx.x;  // B*4*P*HALF = 393216
    if (e >= B_ * 4 * P_ * HALF_) return;
    int j = e % HALF_;
    int r = e / HALF_;                               // (b*4+g)*P + p
    int s = sp[r];
    double invf = exp2(-20.0 * (double)j / 384.0);   // MAX_POS^(-j/half)
    double ang = (double)s * invf;
    cs[e] = make_float2((float)cos(ang), (float)sin(ang));
}

// ---------------- B: junction GEMM (dominant kernel) ----------------
// block = one (b, sign, t). Computes softplus(pdl . pal) for 128x128 (d,a),
// writes W1[b][sign][t][d][a] into the mask half of d_out (staging).
#define KP   16   // rope pairs per K-chunk
#define KL   32   // kl values per chunk (2 per pair)
#define TSTR 34   // LDS tile stride (floats): conflict-free, float2-aligned

__global__ __launch_bounds__(256) void junction_gemm(
    const float* __restrict__ xh, const float2* __restrict__ cs,
    const float* __restrict__ rpd, const float* __restrict__ rpa,
    const float* __restrict__ rnd, const float* __restrict__ rna,
    const int* __restrict__ org, const int* __restrict__ sp,
    float* __restrict__ w1) {
    __shared__ float scof[4 * H_];   // scD | ofD | scA | ofA
    __shared__ float tD[P_ * TSTR];
    __shared__ float tA[P_ * TSTR];
    __shared__ int vD[P_], vA[P_];

    int blk = blockIdx.x;            // b*(2T) + sign*T + t
    int t = blk % T_;
    int sign = (blk / T_) & 1;
    int b = blk / (2 * T_);
    int o = org[b];
    int gd = sign * 2, ga = sign * 2 + 1;
    const float* pd = sign ? rnd : rpd;
    const float* pa = sign ? rna : rpa;
    int tid = threadIdx.x;

    const float* sc_d = pd + ((size_t)(o * 2 + 0) * T_ + t) * H_;
    const float* of_d = pd + ((size_t)(o * 2 + 1) * T_ + t) * H_;
    const float* sc_a = pa + ((size_t)(o * 2 + 0) * T_ + t) * H_;
    const float* of_a = pa + ((size_t)(o * 2 + 1) * T_ + t) * H_;
    for (int e = tid; e < H_; e += 256) {
        scof[e]          = sc_d[e];
        scof[H_ + e]     = of_d[e];
        scof[2 * H_ + e] = sc_a[e];
        scof[3 * H_ + e] = of_a[e];
    }
    if (tid < P_) {
        vD[tid] = sp[(b * 4 + gd) * P_ + tid] >= 0;
        vA[tid] = sp[(b * 4 + ga) * P_ + tid] >= 0;
    }
    const float*  xd = xh + ((size_t)(b * 4 + gd) * P_) * H_;
    const float*  xa = xh + ((size_t)(b * 4 + ga) * P_) * H_;
    const float2* cd = cs + ((size_t)(b * 4 + gd) * P_) * HALF_;
    const float2* ca = cs + ((size_t)(b * 4 + ga) * P_) * HALF_;

    int tx = tid & 15, ty = tid >> 4;
    float acc[8][8] = {};

    for (int j0 = 0; j0 < HALF_; j0 += KP) {
        __syncthreads();   // tiles free from previous chunk's reads
        for (int e = tid; e < P_ * KP; e += 256) {
            int p = e >> 4, jj = e & 15;
            int j = j0 + jj;
            // donor
            float u1 = xd[p * H_ + j], u2 = xd[p * H_ + j + HALF_];
            u1 = scof[j] * u1 + scof[H_ + j];
            u2 = scof[j + HALF_] * u2 + scof[H_ + j + HALF_];
            float2 csv = cd[p * HALF_ + j];
            tD[p * TSTR + 2 * jj]     = u1 * csv.x - u2 * csv.y;
            tD[p * TSTR + 2 * jj + 1] = u1 * csv.y + u2 * csv.x;
            // acceptor
            u1 = xa[p * H_ + j]; u2 = xa[p * H_ + j + HALF_];
            u1 = scof[2 * H_ + j] * u1 + scof[3 * H_ + j];
            u2 = scof[2 * H_ + j + HALF_] * u2 + scof[3 * H_ + j + HALF_];
            csv = ca[p * HALF_ + j];
            tA[p * TSTR + 2 * jj]     = u1 * csv.x - u2 * csv.y;
            tA[p * TSTR + 2 * jj + 1] = u1 * csv.y + u2 * csv.x;
        }
        __syncthreads();
        for (int kl = 0; kl < KL; kl += 2) {
            float2 dv[8], av[8];
            #pragma unroll
            for (int i = 0; i < 8; ++i)
                dv[i] = *(const float2*)&tD[(ty + 16 * i) * TSTR + kl];
            #pragma unroll
            for (int j = 0; j < 8; ++j)
                av[j] = *(const float2*)&tA[(tx + 16 * j) * TSTR + kl];
            #pragma unroll
            for (int i = 0; i < 8; ++i)
                #pragma unroll
                for (int j = 0; j < 8; ++j)
                    acc[i][j] += dv[i].x * av[j].x + dv[i].y * av[j].y;
        }
    }

    float* dst = w1 + (((size_t)(b * 2 + sign) * T_ + t) * P_) * P_;
    for (int i = 0; i < 8; ++i) {
        int d = ty + 16 * i;
        for (int j = 0; j < 8; ++j) {
            int a = tx + 16 * j;
            float x = acc[i][j];
            float v = 0.0f;
            if (vD[d] && vA[a]) v = (x > 15.0f) ? x : log1pf(expf(x));
            dst[d * P_ + a] = v;
        }
    }
}

// ---------------- C: transpose [b][sign][t][d][a] -> [b][d][a][sign*T+t] ----------------
__global__ __launch_bounds__(256) void transpose_out(const float* __restrict__ w1,
                                                     float* __restrict__ pred) {
    __shared__ float tile[64 * 129];
    int blk = blockIdx.x;            // bs*128*6 + d*6 + tt   (3072 blocks)
    int tt = blk % 6;
    int d = (blk / 6) % P_;
    int bs = blk / (6 * P_);         // b*2+sign
    int b = bs >> 1, sign = bs & 1;
    int t0 = tt * 64;
    int tcnt = min(64, T_ - t0);
    int tid = threadIdx.x;

    const float* src = w1 + ((size_t)bs * T_ * P_ + d) * P_;
    for (int e = tid; e < tcnt * P_; e += 256) {
        int i = e >> 7, a = e & 127;
        tile[i * 129 + a] = src[(size_t)(t0 + i) * P_ * P_ + a];
    }
    __syncthreads();
    float* dst = pred + ((size_t)(b * P_ + d) * P_) * TT_ + sign * T_ + t0;
    for (int e = tid; e < P_ * 64; e += 256) {
        int a = e >> 6, ii = e & 63;
        if (ii < tcnt) dst[(size_t)a * TT_ + ii] = tile[ii * 129 + a];
    }
}

// ---------------- D: mask fill ----------------
__global__ void mask_fill(const int* __restrict__ sp, float* __restrict__ mask) {
    int blk = blockIdx.x;            // (b*128+d)*128+a   (32768 blocks)
    int a = blk & 127;
    int d = (blk >> 7) & 127;
    int b = blk >> 14;
    bool vp = (sp[(b * 4 + 0) * P_ + d] >= 0) && (sp[(b * 4 + 1) * P_ + a] >= 0);
    bool vn = (sp[(b * 4 + 2) * P_ + d] >= 0) && (sp[(b * 4 + 3) * P_ + a] >= 0);
    float* dst = mask + (size_t)blk * TT_;
    for (int st = threadIdx.x; st < TT_; st += blockDim.x)
        dst[st] = (st < T_ ? vp : vn) ? 1.0f : 0.0f;
}

extern "C" void kernel_launch(void* const* d_in, const int* in_sizes, int n_in,
                              void* d_out, int out_size, void* d_ws, size_t ws_size,
                              hipStream_t stream) {
    const float* emb  = (const float*)d_in[0];
    const float* w    = (const float*)d_in[1];
    const float* bias = (const float*)d_in[2];
    const float* rpd  = (const float*)d_in[3];
    const float* rpa  = (const float*)d_in[4];
    const float* rnd  = (const float*)d_in[5];
    const float* rna  = (const float*)d_in[6];
    const int*   org  = (const int*)d_in[7];
    const int*   sp   = (const int*)d_in[8];

    float* out = (float*)d_out;
    float* ws  = (float*)d_ws;
    float* xc  = ws + XC_OFF;
    float* xh  = ws + XH_OFF;
    float2* cs = (float2*)(ws + CS_OFF);
    float* pred  = out;
    float* maskp = out + PRED_ELEMS;
    float* w1    = maskp;            // stage [b][sign][t][d][a] in mask half

    gather_cols<<<1024, 256, 0, stream>>>(emb, sp, xc);
    dim3 g1(2, 8, 12);
    small_gemm<<<g1, 256, 0, stream>>>(xc, w, bias, org, xh);
    rope_table<<<1536, 256, 0, stream>>>(sp, cs);
    junction_gemm<<<2 * 2 * T_, 256, 0, stream>>>(xh, cs, rpd, rpa, rnd, rna, org, sp, w1);
    transpose_out<<<2 * 2 * P_ * 6, 256, 0, stream>>>(w1, pred);
    mask_fill<<<32768, 256, 0, stream>>>(sp, maskp);
}

// Round 2
// 609.148 us; speedup vs baseline: 1.8754x; 1.8754x over previous
//
#include <hip/hip_runtime.h>
#include <hip/hip_bf16.h>
#include <math.h>
#include <string.h>

#define B_    2
#define C_    1536
#define S_    16384
#define H_    768
#define T_    367
#define P_    128
#define HALF_ 384
#define TT_   734                 // 2*T
#define PRED_ELEMS 24051712      // B*P*P*2T

// ws layout (float offsets)
#define XC_OFF 0                 // [B][4][P][C]   1,572,864 floats
#define XH_OFF 1572864           // [B][4][P][H]     786,432 floats
#define CS_OFF 2359296           // [B][4][P][HALF] float2  786,432 floats

typedef short short8 __attribute__((ext_vector_type(8)));
typedef float f32x4  __attribute__((ext_vector_type(4)));

// ---------------- A0: gather embedding columns ----------------
__global__ void gather_cols(const float* __restrict__ emb,
                            const int* __restrict__ sp,
                            float* __restrict__ xc) {
    int blk = blockIdx.x;           // B*4*P = 1024
    int p = blk & 127;
    int g = (blk >> 7) & 3;
    int b = blk >> 9;
    int s = sp[(b * 4 + g) * P_ + p];
    const float* src = emb + (size_t)b * C_ * S_ + s;
    float* dst = xc + ((size_t)(b * 4 + g) * P_ + p) * C_;
    for (int c = threadIdx.x; c < C_; c += blockDim.x)
        dst[c] = src[(size_t)c * S_];
}

// ---------------- A1: gathered-logits GEMM + bias ----------------
__global__ __launch_bounds__(256) void small_gemm(const float* __restrict__ xc,
                                                  const float* __restrict__ w,
                                                  const float* __restrict__ bias,
                                                  const int* __restrict__ org,
                                                  float* __restrict__ xh) {
    __shared__ float Xs[64][33];
    __shared__ float Ws[64][33];
    int b = blockIdx.x, rt = blockIdx.y, ht = blockIdx.z;
    int o = org[b];
    int row0 = b * 512 + rt * 64;
    int h0 = ht * 64;
    int tid = threadIdx.x;
    int tx = tid & 15, ty = tid >> 4;
    float acc[4][4] = {};
    for (int k0 = 0; k0 < C_; k0 += 32) {
        for (int e = tid; e < 64 * 32; e += 256) {
            int i = e >> 5, k = e & 31;
            Xs[i][k] = xc[(size_t)(row0 + i) * C_ + k0 + k];
            Ws[i][k] = w[((size_t)o * H_ + h0 + i) * C_ + k0 + k];
        }
        __syncthreads();
        for (int k = 0; k < 32; ++k) {
            float a_[4], b_[4];
            #pragma unroll
            for (int u = 0; u < 4; ++u) a_[u] = Xs[ty * 4 + u][k];
            #pragma unroll
            for (int v = 0; v < 4; ++v) b_[v] = Ws[tx * 4 + v][k];
            #pragma unroll
            for (int u = 0; u < 4; ++u)
                #pragma unroll
                for (int v = 0; v < 4; ++v) acc[u][v] += a_[u] * b_[v];
        }
        __syncthreads();
    }
    for (int u = 0; u < 4; ++u)
        for (int v = 0; v < 4; ++v) {
            int r = row0 + ty * 4 + u, h = h0 + tx * 4 + v;
            xh[(size_t)r * H_ + h] = acc[u][v] + bias[o * H_ + h];
        }
}

// ---------------- A2: RoPE cos/sin table (fp64 trig for accuracy) ----------------
__global__ void rope_table(const int* __restrict__ sp, float2* __restrict__ cs) {
    int e = blockIdx.x * blockDim.x + threadIdx.x;  // B*4*P*HALF = 393216
    if (e >= B_ * 4 * P_ * HALF_) return;
    int j = e % HALF_;
    int r = e / HALF_;                               // (b*4+g)*P + p
    int s = sp[r];
    double invf = exp2(-20.0 * (double)j / 384.0);   // MAX_POS^(-j/half)
    double ang = (double)s * invf;
    cs[e] = make_float2((float)cos(ang), (float)sin(ang));
}

// ---------------- B: junction GEMM via bf16 MFMA ----------------
// block = one (b, sign, t); 4 waves, each 64x64 of the 128x128 output.
// K=768 processed as 12 chunks of 64 (32 rope pairs), tiles built in bf16 LDS.
#define KCP 32          // rope pairs per chunk
#define KCL 64          // k-values per chunk
#define TSTR2 72        // LDS tile stride (ushorts): 144B rows -> 16B aligned, 2-way banks

__global__ __launch_bounds__(256) void junction_mfma(
    const float* __restrict__ xh, const float2* __restrict__ cs,
    const float* __restrict__ rpd, const float* __restrict__ rpa,
    const float* __restrict__ rnd, const float* __restrict__ rna,
    const int* __restrict__ org, const int* __restrict__ sp,
    float* __restrict__ w1) {
    __shared__ float scof[4 * H_];                 // scD | ofD | scA | ofA
    __shared__ unsigned short tD[P_ * TSTR2];
    __shared__ unsigned short tA[P_ * TSTR2];
    __shared__ int vD[P_], vA[P_];

    int blk = blockIdx.x;            // b*(2T) + sign*T + t
    int t = blk % T_;
    int sign = (blk / T_) & 1;
    int b = blk / (2 * T_);
    int o = org[b];
    int gd = sign * 2, ga = sign * 2 + 1;
    const float* pd = sign ? rnd : rpd;
    const float* pa = sign ? rna : rpa;
    int tid = threadIdx.x;

    const float* sc_d = pd + ((size_t)(o * 2 + 0) * T_ + t) * H_;
    const float* of_d = pd + ((size_t)(o * 2 + 1) * T_ + t) * H_;
    const float* sc_a = pa + ((size_t)(o * 2 + 0) * T_ + t) * H_;
    const float* of_a = pa + ((size_t)(o * 2 + 1) * T_ + t) * H_;
    for (int e = tid; e < H_; e += 256) {
        scof[e]          = sc_d[e];
        scof[H_ + e]     = of_d[e];
        scof[2 * H_ + e] = sc_a[e];
        scof[3 * H_ + e] = of_a[e];
    }
    if (tid < P_) {
        vD[tid] = sp[(b * 4 + gd) * P_ + tid] >= 0;
        vA[tid] = sp[(b * 4 + ga) * P_ + tid] >= 0;
    }
    const float*  xd = xh + ((size_t)(b * 4 + gd) * P_) * H_;
    const float*  xa = xh + ((size_t)(b * 4 + ga) * P_) * H_;
    const float2* cd = cs + ((size_t)(b * 4 + gd) * P_) * HALF_;
    const float2* ca = cs + ((size_t)(b * 4 + ga) * P_) * HALF_;

    int lane = tid & 63, wid = tid >> 6;
    int wrow = (wid >> 1) * 64, wcol = (wid & 1) * 64;
    int lr = lane & 15, lq = lane >> 4;

    f32x4 acc[4][4];
    #pragma unroll
    for (int i = 0; i < 4; ++i)
        #pragma unroll
        for (int j = 0; j < 4; ++j)
            acc[i][j] = (f32x4){0.f, 0.f, 0.f, 0.f};

    int jj = tid & 31;        // pair within chunk (fixed per thread)
    int prow = tid >> 5;      // 0..7

    __syncthreads();          // scof/vD/vA ready

    for (int ch = 0; ch < 12; ++ch) {
        int j = ch * KCP + jj;
        if (ch) __syncthreads();   // previous chunk's MFMA reads done

        // ---- build donor tile ----
        {
            float s1 = scof[j], o1 = scof[H_ + j];
            float s2 = scof[j + HALF_], o2 = scof[H_ + j + HALF_];
            #pragma unroll 4
            for (int pass = 0; pass < 16; ++pass) {
                int p = pass * 8 + prow;
                float u1 = fmaf(s1, xd[p * H_ + j], o1);
                float u2 = fmaf(s2, xd[p * H_ + j + HALF_], o2);
                float2 cv = cd[p * HALF_ + j];
                float r1 = u1 * cv.x - u2 * cv.y;
                float r2 = u1 * cv.y + u2 * cv.x;
                __hip_bfloat162 h = __float22bfloat162_rn(make_float2(r1, r2));
                unsigned int wbits;
                __builtin_memcpy(&wbits, &h, 4);
                *(unsigned int*)&tD[p * TSTR2 + 2 * jj] = wbits;
            }
        }
        // ---- build acceptor tile ----
        {
            float s1 = scof[2 * H_ + j], o1 = scof[3 * H_ + j];
            float s2 = scof[2 * H_ + j + HALF_], o2 = scof[3 * H_ + j + HALF_];
            #pragma unroll 4
            for (int pass = 0; pass < 16; ++pass) {
                int p = pass * 8 + prow;
                float u1 = fmaf(s1, xa[p * H_ + j], o1);
                float u2 = fmaf(s2, xa[p * H_ + j + HALF_], o2);
                float2 cv = ca[p * HALF_ + j];
                float r1 = u1 * cv.x - u2 * cv.y;
                float r2 = u1 * cv.y + u2 * cv.x;
                __hip_bfloat162 h = __float22bfloat162_rn(make_float2(r1, r2));
                unsigned int wbits;
                __builtin_memcpy(&wbits, &h, 4);
                *(unsigned int*)&tA[p * TSTR2 + 2 * jj] = wbits;
            }
        }
        __syncthreads();

        // ---- MFMA: 2 k-steps of 32 ----
        #pragma unroll
        for (int kk = 0; kk < KCL; kk += 32) {
            short8 af[4], bfr[4];
            #pragma unroll
            for (int fi = 0; fi < 4; ++fi)
                af[fi] = *(const short8*)&tD[(wrow + fi * 16 + lr) * TSTR2 + kk + lq * 8];
            #pragma unroll
            for (int fj = 0; fj < 4; ++fj)
                bfr[fj] = *(const short8*)&tA[(wcol + fj * 16 + lr) * TSTR2 + kk + lq * 8];
            #pragma unroll
            for (int fi = 0; fi < 4; ++fi)
                #pragma unroll
                for (int fj = 0; fj < 4; ++fj)
                    acc[fi][fj] = __builtin_amdgcn_mfma_f32_16x16x32_bf16(
                        af[fi], bfr[fj], acc[fi][fj], 0, 0, 0);
        }
    }

    // ---- epilogue: softplus + mask, write staged [b][sign][t][d][a] ----
    float* dst = w1 + (((size_t)(b * 2 + sign) * T_ + t) * P_) * P_;
    #pragma unroll
    for (int fi = 0; fi < 4; ++fi) {
        #pragma unroll
        for (int r = 0; r < 4; ++r) {
            int d = wrow + fi * 16 + lq * 4 + r;
            int vd = vD[d];
            #pragma unroll
            for (int fj = 0; fj < 4; ++fj) {
                int a = wcol + fj * 16 + lr;
                float x = acc[fi][fj][r];
                float v = 0.0f;
                if (vd && vA[a]) v = (x > 15.0f) ? x : log1pf(expf(x));
                dst[d * P_ + a] = v;
            }
        }
    }
}

// ---------------- C: transpose [b][sign][t][d][a] -> [b][d][a][sign*T+t] ----------------
__global__ __launch_bounds__(256) void transpose_out(const float* __restrict__ w1,
                                                     float* __restrict__ pred) {
    __shared__ float tile[64 * 129];
    int blk = blockIdx.x;            // bs*128*6 + d*6 + tt   (3072 blocks)
    int tt = blk % 6;
    int d = (blk / 6) % P_;
    int bs = blk / (6 * P_);         // b*2+sign
    int b = bs >> 1, sign = bs & 1;
    int t0 = tt * 64;
    int tcnt = min(64, T_ - t0);
    int tid = threadIdx.x;

    const float* src = w1 + ((size_t)bs * T_ * P_ + d) * P_;
    for (int e = tid; e < tcnt * P_; e += 256) {
        int i = e >> 7, a = e & 127;
        tile[i * 129 + a] = src[(size_t)(t0 + i) * P_ * P_ + a];
    }
    __syncthreads();
    float* dst = pred + ((size_t)(b * P_ + d) * P_) * TT_ + sign * T_ + t0;
    for (int e = tid; e < P_ * 64; e += 256) {
        int a = e >> 6, ii = e & 63;
        if (ii < tcnt) dst[(size_t)a * TT_ + ii] = tile[ii * 129 + a];
    }
}

// ---------------- D: mask fill ----------------
__global__ void mask_fill(const int* __restrict__ sp, float* __restrict__ mask) {
    int blk = blockIdx.x;            // (b*128+d)*128+a   (32768 blocks)
    int a = blk & 127;
    int d = (blk >> 7) & 127;
    int b = blk >> 14;
    bool vp = (sp[(b * 4 + 0) * P_ + d] >= 0) && (sp[(b * 4 + 1) * P_ + a] >= 0);
    bool vn = (sp[(b * 4 + 2) * P_ + d] >= 0) && (sp[(b * 4 + 3) * P_ + a] >= 0);
    float* dst = mask + (size_t)blk * TT_;
    for (int st = threadIdx.x; st < TT_; st += blockDim.x)
        dst[st] = (st < T_ ? vp : vn) ? 1.0f : 0.0f;
}

extern "C" void kernel_launch(void* const* d_in, const int* in_sizes, int n_in,
                              void* d_out, int out_size, void* d_ws, size_t ws_size,
                              hipStream_t stream) {
    const float* emb  = (const float*)d_in[0];
    const float* w    = (const float*)d_in[1];
    const float* bias = (const float*)d_in[2];
    const float* rpd  = (const float*)d_in[3];
    const float* rpa  = (const float*)d_in[4];
    const float* rnd  = (const float*)d_in[5];
    const float* rna  = (const float*)d_in[6];
    const int*   org  = (const int*)d_in[7];
    const int*   sp   = (const int*)d_in[8];

    float* out = (float*)d_out;
    float* ws  = (float*)d_ws;
    float* xc  = ws + XC_OFF;
    float* xh  = ws + XH_OFF;
    float2* cs = (float2*)(ws + CS_OFF);
    float* pred  = out;
    float* maskp = out + PRED_ELEMS;
    float* w1    = maskp;            // stage [b][sign][t][d][a] in mask half

    gather_cols<<<1024, 256, 0, stream>>>(emb, sp, xc);
    dim3 g1(2, 8, 12);
    small_gemm<<<g1, 256, 0, stream>>>(xc, w, bias, org, xh);
    rope_table<<<1536, 256, 0, stream>>>(sp, cs);
    junction_mfma<<<2 * 2 * T_, 256, 0, stream>>>(xh, cs, rpd, rpa, rnd, rna, org, sp, w1);
    transpose_out<<<2 * 2 * P_ * 6, 256, 0, stream>>>(w1, pred);
    mask_fill<<<32768, 256, 0, stream>>>(sp, maskp);
}